// Round 1
// baseline (2565.972 us; speedup 1.0000x reference)
//
#include <hip/hip_runtime.h>
#include <hip/hip_bf16.h>
#include <cstdint>

typedef __hip_bfloat16 bf16;
typedef __attribute__((ext_vector_type(8))) short short8;
typedef __attribute__((ext_vector_type(4))) float floatx4;

#define AS1 __attribute__((address_space(1)))
#define AS3 __attribute__((address_space(3)))

__device__ __forceinline__ int imin(int a, int b) { return a < b ? a : b; }

__device__ __forceinline__ void async_copy16(const void* g, void* l) {
  __builtin_amdgcn_global_load_lds((const AS1 uint32_t*)g, (AS3 uint32_t*)l, 16, 0, 0);
}

// ---------------------------------------------------------------------------
// W [h][in][out] fp32  ->  Wt [h][out][in] bf16   (1600x1600 per head)
// grid (25, 25, 8), block 256
__global__ __launch_bounds__(256) void transpose_w(const float* __restrict__ W,
                                                   bf16* __restrict__ Wt) {
  __shared__ float tile[64][65];
  const float* Wh = W + (size_t)blockIdx.z * 2560000;
  bf16* Wth = Wt + (size_t)blockIdx.z * 2560000;
  const int i0 = blockIdx.x * 64;  // in-dim base
  const int o0 = blockIdx.y * 64;  // out-dim base
  for (int e = threadIdx.x; e < 4096; e += 256) {
    int r = e >> 6, c = e & 63;  // r: in offset, c: out offset
    tile[r][c] = Wh[(size_t)(i0 + r) * 1600 + o0 + c];
  }
  __syncthreads();
  for (int e = threadIdx.x; e < 4096; e += 256) {
    int r = e >> 6, c = e & 63;  // r: out offset, c: in offset
    Wth[(size_t)(o0 + r) * 1600 + i0 + c] = __float2bfloat16(tile[c][r]);
  }
}

// ---------------------------------------------------------------------------
// x [N][64][256][25] fp32 -> xf [n*256+t][c*25+v] bf16
// grid (2, 32, 32): (c-block of 32, t-chunk of 8, n), block 256
__global__ __launch_bounds__(256) void pack_x(const float* __restrict__ X,
                                              bf16* __restrict__ Xf) {
  __shared__ float tile[32 * 200];  // [c_local][t_local*25+v]
  const int n = blockIdx.z, tb = blockIdx.y * 8, cb = blockIdx.x * 32;
  const float* Xn = X + (size_t)n * 64 * 6400;
  for (int e = threadIdx.x; e < 6400; e += 256) {
    int c = e / 200, rv = e % 200;  // rv = t_local*25 + v, contiguous in x
    tile[e] = Xn[(size_t)(cb + c) * 6400 + tb * 25 + rv];
  }
  __syncthreads();
  bf16* dst = Xf + ((size_t)n * 256 + tb) * 1600 + cb * 25;
  for (int e = threadIdx.x; e < 6400; e += 256) {
    int t = e / 800, j = e % 800;  // j = c_local*25 + v
    int c = j / 25, v = j % 25;
    dst[(size_t)t * 1600 + j] = __float2bfloat16(tile[c * 200 + t * 25 + v]);
  }
}

// ---------------------------------------------------------------------------
// Shared 128x128 bf16 MFMA GEMM core, B in transposed ([N][K]) form.
// MODE 0: K/Q proj  A=act[8192,1600] B=Wt_h[1600,1600] +bias(col) -> [n,h,t,d] bf16
// MODE 1: Vt proj   A=Wvt_h[1600,1600] B=mf[8192,1600] +bias(row) -> [n,h,d,t] bf16
// MODE 2: QK^T      per z=(n,h): A=Q[256,1600] B=K[256,1600], *scale -> att fp32
// MODE 3: PV        per z=(n,h): A=P[256,256]  B=Vt[1600,256]       -> y bf16
template <int MODE>
__global__ __launch_bounds__(256) void gemm_bt(const short* __restrict__ Abase,
                                               const short* __restrict__ Bbase,
                                               const float* __restrict__ biasBase,
                                               void* __restrict__ outBase) {
  constexpr int M = (MODE == 0) ? 8192 : (MODE == 1) ? 1600 : 256;
  constexpr int N = (MODE == 0) ? 1600 : (MODE == 1) ? 8192 : (MODE == 2) ? 256 : 1600;
  constexpr int K = (MODE == 3) ? 256 : 1600;

  const int z = blockIdx.z;
  const short* A;
  const short* B;
  const float* bias = nullptr;
  if constexpr (MODE == 0) { A = Abase; B = Bbase + (size_t)z * 2560000; bias = biasBase + z * 1600; }
  if constexpr (MODE == 1) { A = Abase + (size_t)z * 2560000; B = Bbase; bias = biasBase + z * 1600; }
  if constexpr (MODE == 2) { A = Abase + (size_t)z * 409600; B = Bbase + (size_t)z * 409600; }
  if constexpr (MODE == 3) { A = Abase + (size_t)z * 65536; B = Bbase + (size_t)z * 409600; }

  __shared__ short As[128 * 32];
  __shared__ short Bs[128 * 32];

  const int tid = threadIdx.x;
  const int lane = tid & 63;
  const int wv = tid >> 6;
  const int m0 = blockIdx.x * 128;
  const int n0 = blockIdx.y * 128;

  // staging: each wave issues 2 chunks per tile; lane covers 16B (8 bf16)
  const int srow = wv * 32 + (lane >> 2);
  const int scol = (lane & 3) * 8;
  const short* Ag0 = A + (size_t)imin(m0 + srow, M - 1) * K + scol;
  const short* Ag1 = A + (size_t)imin(m0 + srow + 16, M - 1) * K + scol;
  const short* Bg0 = B + (size_t)imin(n0 + srow, N - 1) * K + scol;
  const short* Bg1 = B + (size_t)imin(n0 + srow + 16, N - 1) * K + scol;

  short* Asw = &As[wv * 1024];
  short* Bsw = &Bs[wv * 1024];

  const int fr = lane & 15;          // m (A) / n (B) within 16x16 tile
  const int fk = (lane >> 4) * 8;    // k offset within 32
  const int wm = (wv & 1) * 64;
  const int wn = (wv >> 1) * 64;

  floatx4 acc[4][4] = {};

  for (int k = 0; k < K; k += 32) {
    async_copy16(Ag0 + k, Asw);
    async_copy16(Ag1 + k, Asw + 512);
    async_copy16(Bg0 + k, Bsw);
    async_copy16(Bg1 + k, Bsw + 512);
    __syncthreads();
    short8 af[4], bfr[4];
#pragma unroll
    for (int i = 0; i < 4; i++) af[i] = *(const short8*)&As[(wm + i * 16 + fr) * 32 + fk];
#pragma unroll
    for (int j = 0; j < 4; j++) bfr[j] = *(const short8*)&Bs[(wn + j * 16 + fr) * 32 + fk];
#pragma unroll
    for (int i = 0; i < 4; i++)
#pragma unroll
      for (int j = 0; j < 4; j++)
        acc[i][j] = __builtin_amdgcn_mfma_f32_16x16x32_bf16(af[i], bfr[j], acc[i][j], 0, 0, 0);
    __syncthreads();
  }

  const int q4 = (lane >> 4) * 4;
#pragma unroll
  for (int i = 0; i < 4; i++) {
#pragma unroll
    for (int j = 0; j < 4; j++) {
#pragma unroll
      for (int r = 0; r < 4; r++) {
        const int mm = m0 + wm + i * 16 + q4 + r;
        const int nn = n0 + wn + j * 16 + fr;
        float v = acc[i][j][r];
        if constexpr (MODE == 0) {
          if (nn < 1600) {
            v += bias[nn];
            const int nb = mm >> 8, t = mm & 255;
            ((bf16*)outBase)[(((size_t)nb * 8 + z) * 256 + t) * 1600 + nn] = __float2bfloat16(v);
          }
        } else if constexpr (MODE == 1) {
          if (mm < 1600) {
            v += bias[mm];
            const int nb = nn >> 8, t = nn & 255;
            ((bf16*)outBase)[(((size_t)nb * 8 + z) * 1600 + mm) * 256 + t] = __float2bfloat16(v);
          }
        } else if constexpr (MODE == 2) {
          ((float*)outBase)[((size_t)z * 256 + mm) * 256 + nn] = v * 0.025f;  // 1/sqrt(1600)
        } else {
          if (nn < 1600)
            ((bf16*)outBase)[((size_t)z * 256 + mm) * 1600 + nn] = __float2bfloat16(v);
        }
      }
    }
  }
}

// ---------------------------------------------------------------------------
// softmax over heads: att [n][h][q][k] fp32 -> P [n][h][q][k] bf16
// grid 8192, block 256; thread = one (n, q, k)
__global__ __launch_bounds__(256) void softmax_h(const float* __restrict__ att,
                                                 bf16* __restrict__ P) {
  const size_t idx = (size_t)blockIdx.x * 256 + threadIdx.x;  // 32*65536
  const int n = (int)(idx >> 16);
  const int rem = (int)(idx & 65535);
  const float* a = att + (size_t)n * 8 * 65536 + rem;
  float v[8];
  float mx = -1e30f;
#pragma unroll
  for (int h = 0; h < 8; h++) {
    v[h] = a[(size_t)h * 65536];
    mx = fmaxf(mx, v[h]);
  }
  float s = 0.f;
#pragma unroll
  for (int h = 0; h < 8; h++) {
    v[h] = __expf(v[h] - mx);
    s += v[h];
  }
  const float inv = 1.f / s;
  bf16* p = P + (size_t)n * 8 * 65536 + rem;
#pragma unroll
  for (int h = 0; h < 8; h++) p[(size_t)h * 65536] = __float2bfloat16(v[h] * inv);
}

// ---------------------------------------------------------------------------
// y [n][h][t][d=v*64+c] bf16 -> out [n][c*8+h][t][v] fp32
// grid (32 t-chunks, 8 h, 32 n), block 256
__global__ __launch_bounds__(256) void unpack_y(const bf16* __restrict__ Y,
                                                float* __restrict__ out) {
  __shared__ bf16 tile[8 * 1600];
  const int tb = blockIdx.x * 8, h = blockIdx.y, n = blockIdx.z;
  const uint32_t* src = (const uint32_t*)(Y + (((size_t)n * 8 + h) * 256 + tb) * 1600);
  uint32_t* td = (uint32_t*)tile;
  for (int e = threadIdx.x; e < 6400; e += 256) td[e] = src[e];
  __syncthreads();
  for (int r = threadIdx.x; r < 512; r += 256) {
    const int c = r >> 3, t = r & 7;
    float* o = out + (((size_t)n * 512 + c * 8 + h) * 256 + tb + t) * 25;
    const bf16* s = tile + t * 1600 + c;
#pragma unroll
    for (int v = 0; v < 25; v++) o[v] = __bfloat162float(s[v * 64]);
  }
}

// ---------------------------------------------------------------------------
extern "C" void kernel_launch(void* const* d_in, const int* in_sizes, int n_in,
                              void* d_out, int out_size, void* d_ws, size_t ws_size,
                              hipStream_t stream) {
  const float* x = (const float*)d_in[0];
  const float* m = (const float*)d_in[1];
  const float* Wk = (const float*)d_in[2];
  const float* bk = (const float*)d_in[3];
  const float* Wq = (const float*)d_in[4];
  const float* bq = (const float*)d_in[5];
  const float* Wv = (const float*)d_in[6];
  const float* bv = (const float*)d_in[7];
  float* out = (float*)d_out;

  char* ws = (char*)d_ws;
  // sizes (bytes): Wt 3*40,960,000; xf/mf 26,214,400 each; K/Q/Vt 209,715,200 each
  bf16* wkt = (bf16*)(ws);
  bf16* wqt = (bf16*)(ws + 40960000ll);
  bf16* wvt = (bf16*)(ws + 81920000ll);
  bf16* xf = (bf16*)(ws + 122880000ll);
  bf16* mf = (bf16*)(ws + 149094400ll);
  bf16* Kb = (bf16*)(ws + 175308800ll);
  bf16* Qb = (bf16*)(ws + 385024000ll);
  bf16* Vt = (bf16*)(ws + 594739200ll);
  // aliases (regions dead by the time these are written):
  float* att = (float*)(ws);            // over wkt/wqt (dead after projections)
  bf16* P = (bf16*)(ws + 67108864ll);   // over wvt tail (dead after Vt proj)
  bf16* Yb = Qb;                        // Q dead after QK^T

  transpose_w<<<dim3(25, 25, 8), 256, 0, stream>>>(Wk, wkt);
  transpose_w<<<dim3(25, 25, 8), 256, 0, stream>>>(Wq, wqt);
  transpose_w<<<dim3(25, 25, 8), 256, 0, stream>>>(Wv, wvt);
  pack_x<<<dim3(2, 32, 32), 256, 0, stream>>>(x, xf);
  pack_x<<<dim3(2, 32, 32), 256, 0, stream>>>(m, mf);

  gemm_bt<0><<<dim3(64, 13, 8), 256, 0, stream>>>((const short*)xf, (const short*)wkt, bk, Kb);
  gemm_bt<0><<<dim3(64, 13, 8), 256, 0, stream>>>((const short*)mf, (const short*)wqt, bq, Qb);
  gemm_bt<1><<<dim3(13, 64, 8), 256, 0, stream>>>((const short*)wvt, (const short*)mf, bv, Vt);

  gemm_bt<2><<<dim3(2, 2, 256), 256, 0, stream>>>((const short*)Qb, (const short*)Kb, nullptr, att);
  softmax_h<<<dim3(8192), 256, 0, stream>>>(att, P);
  gemm_bt<3><<<dim3(2, 13, 256), 256, 0, stream>>>((const short*)P, (const short*)Vt, nullptr, Yb);

  unpack_y<<<dim3(32, 8, 32), 256, 0, stream>>>(Yb, out);
}